// Round 8
// baseline (128.294 us; speedup 1.0000x reference)
//
#include <hip/hip_runtime.h>
#include <hip/hip_bf16.h>

typedef __bf16 v8bf16 __attribute__((ext_vector_type(8)));
typedef float  v4f32  __attribute__((ext_vector_type(4)));

#define MAIN_GRID 512

static __device__ __forceinline__ float silu_f(float v) {
    return v / (1.0f + __expf(-v));
}

static __device__ __forceinline__ v8bf16 cvt8(v4f32 f0, v4f32 f1) {
    v8bf16 t;
    t[0] = (__bf16)f0[0]; t[1] = (__bf16)f0[1]; t[2] = (__bf16)f0[2]; t[3] = (__bf16)f0[3];
    t[4] = (__bf16)f1[0]; t[5] = (__bf16)f1[1]; t[6] = (__bf16)f1[2]; t[7] = (__bf16)f1[3];
    return t;
}

__global__ void zero_ws_kernel(float* __restrict__ ws, int n) {
    int i = blockIdx.x * blockDim.x + threadIdx.x;
    if (i < n) ws[i] = 0.0f;
}

// Load this wave's 16-row A-slice for chunk cc straight into VGPRs.
static __device__ __forceinline__ void stage_regs(
    const float* __restrict__ x, int N, long cc, int w, int l15, int lg,
    v4f32 (&st)[8])
{
    int arow = (int)(cc * 64) + w * 16 + l15;
    if (arow >= N) arow = N - 1;
    const float* xrow = x + (long)arow * 128 + lg * 8;
#pragma unroll
    for (int kt = 0; kt < 4; ++kt) {
        st[2 * kt]     = *reinterpret_cast<const v4f32*>(xrow + kt * 32);
        st[2 * kt + 1] = *reinterpret_cast<const v4f32*>(xrow + kt * 32 + 4);
    }
}

// One pipeline slot of the PURE-STREAM MLP kernel: consume st (staged 2
// slots ago) -> restage for cnx -> MFMA -> reduce -> coalesced xo store.
// No atomics / gathers / LDS / barriers anywhere.
static __device__ __forceinline__ void process_slot(
    const float* __restrict__ x, float* __restrict__ xobuf,
    const v8bf16 (&bf)[4][4], const float (&b1v)[4], const float (&w2v)[4],
    float b2s, int N, long nChunks,
    int w, int lane, int l15, int lg,
    v4f32 (&st)[8], long cc, long cnx)
{
    // 1. consume staged regs (issued 2 slots ago -> wait is a no-op)
    v8bf16 af[4];
#pragma unroll
    for (int kt = 0; kt < 4; ++kt)
        af[kt] = cvt8(st[2 * kt], st[2 * kt + 1]);

    // 2. restage st for chunk cnx (2 slots ahead)
    if (cnx < nChunks) stage_regs(x, N, cnx, w, l15, lg, st);

    // 3. MFMA: acc[ct] += A(16x32) * W1(32x16) over 4 k-tiles
    v4f32 acc[4];
#pragma unroll
    for (int ct = 0; ct < 4; ++ct) acc[ct] = (v4f32){0.f, 0.f, 0.f, 0.f};
#pragma unroll
    for (int kt = 0; kt < 4; ++kt) {
#pragma unroll
        for (int ct = 0; ct < 4; ++ct)
            acc[ct] = __builtin_amdgcn_mfma_f32_16x16x32_bf16(af[kt], bf[kt][ct], acc[ct], 0, 0, 0);
    }

    // 4. xo = silu(acc+b1).w2 reduced over the 64 channels
    float part0 = 0.f, part1 = 0.f, part2 = 0.f, part3 = 0.f;
#pragma unroll
    for (int ct = 0; ct < 4; ++ct) {
        part0 += silu_f(acc[ct][0] + b1v[ct]) * w2v[ct];
        part1 += silu_f(acc[ct][1] + b1v[ct]) * w2v[ct];
        part2 += silu_f(acc[ct][2] + b1v[ct]) * w2v[ct];
        part3 += silu_f(acc[ct][3] + b1v[ct]) * w2v[ct];
    }
#pragma unroll
    for (int d = 1; d < 16; d <<= 1) {
        part0 += __shfl_xor(part0, d);
        part1 += __shfl_xor(part1, d);
        part2 += __shfl_xor(part2, d);
        part3 += __shfl_xor(part3, d);
    }
    const int srcl = (l15 >> 2) << 4;
    float t0 = __shfl(part0, srcl);
    float t1 = __shfl(part1, srcl);
    float t2 = __shfl(part2, srcl);
    float t3 = __shfl(part3, srcl);
    const int rr = lane & 3;
    float xo = ((rr == 0) ? t0 : (rr == 1) ? t1 : (rr == 2) ? t2 : t3) + b2s;

    // 5. coalesced store of 16 xo values
    if (lane < 16) {
        int a = (int)(cc * 64) + w * 16 + lane;
        if (a < N) xobuf[a] = xo;
    }
}

__launch_bounds__(256)
__global__ void mlp_kernel(
    const float* __restrict__ x,
    const float* __restrict__ W1, const float* __restrict__ b1,
    const float* __restrict__ W2, const float* __restrict__ b2,
    float* __restrict__ xobuf,
    int N, int nChunks)
{
    const int tid  = threadIdx.x;
    const int lane = tid & 63;
    const int w    = tid >> 6;        // wave 0..3
    const int l15  = lane & 15;
    const int lg   = lane >> 4;

    float b1v[4], w2v[4];
#pragma unroll
    for (int ct = 0; ct < 4; ++ct) {
        b1v[ct] = b1[ct * 16 + l15];
        w2v[ct] = W2[ct * 16 + l15];
    }
    const float b2s = b2[0];

    // W1 fragments, register-resident for the whole kernel
    v8bf16 bf[4][4];
#pragma unroll
    for (int kt = 0; kt < 4; ++kt) {
#pragma unroll
        for (int ct = 0; ct < 4; ++ct) {
            const float* src = W1 + (ct * 16 + l15) * 128 + kt * 32 + lg * 8;
            v4f32 f0 = *reinterpret_cast<const v4f32*>(src);
            v4f32 f1 = *reinterpret_cast<const v4f32*>(src + 4);
            bf[kt][ct] = cvt8(f0, f1);
        }
    }

    const long gs = gridDim.x;
    long c = blockIdx.x;
    if (c >= nChunks) return;

    // ---- prologue: fill both pipeline slots ----
    v4f32 stA[8], stB[8];
#pragma unroll
    for (int i = 0; i < 8; ++i) { stA[i] = (v4f32){0.f,0.f,0.f,0.f}; stB[i] = (v4f32){0.f,0.f,0.f,0.f}; }

    stage_regs(x, N, c, w, l15, lg, stA);
    if (c + gs < nChunks) stage_regs(x, N, c + gs, w, l15, lg, stB);

    // ---- main loop, hand-unrolled x2 (depth-2 ping-pong, static reg indexing) ----
    while (true) {
        process_slot(x, xobuf, bf, b1v, w2v, b2s, N, nChunks,
                     w, lane, l15, lg, stA, c, c + 2 * gs);
        c += gs;
        if (c >= nChunks) break;
        process_slot(x, xobuf, bf, b1v, w2v, b2s, N, nChunks,
                     w, lane, l15, lg, stB, c, c + 2 * gs);
        c += gs;
        if (c >= nChunks) break;
    }
}

// Streaming dipole kernel: full-wave segmented scan over sorted batch ids,
// run-tail atomics into ws[b*8+c]. High occupancy hides its own latency.
__launch_bounds__(256)
__global__ void dipole_kernel(
    const float* __restrict__ pos, const float* __restrict__ am,
    const int* __restrict__ z, const int* __restrict__ batch,
    const float* __restrict__ xo, float* __restrict__ ws,
    int N, int nStripes)
{
    const int lane = threadIdx.x & 63;
    const int gw   = (blockIdx.x * blockDim.x + threadIdx.x) >> 6;
    const int nW   = (gridDim.x * blockDim.x) >> 6;

    for (int s = gw; s < nStripes; s += nW) {
        int a = s * 64 + lane;
        bool valid = (a < N);
        int ac = valid ? a : N - 1;
        float sc = valid ? 1.0f : 0.0f;
        float xov = xo[ac];
        float px = pos[ac * 3 + 0];
        float py = pos[ac * 3 + 1];
        float pz = pos[ac * 3 + 2];
        int   bi = batch[ac];
        float m  = am[z[ac]];

        float v0 = sc * xov * px, v1 = sc * xov * py, v2 = sc * xov * pz, v3 = sc * xov;
        float v4 = sc * m   * px, v5 = sc * m   * py, v6 = sc * m   * pz, v7 = sc * m;

        int bprev = __shfl_up(bi, 1);
        bool head = (lane == 0) || (bi != bprev);
        unsigned long long hm = __ballot(head);
        unsigned long long below = hm & (~0ull >> (63 - lane));
        int rs = 63 - __builtin_clzll(below);   // first lane of my run

#define SCAN_STEP(d)                                                        \
        {                                                                   \
            float u0 = __shfl_up(v0, d), u1 = __shfl_up(v1, d);             \
            float u2 = __shfl_up(v2, d), u3 = __shfl_up(v3, d);             \
            float u4 = __shfl_up(v4, d), u5 = __shfl_up(v5, d);             \
            float u6 = __shfl_up(v6, d), u7 = __shfl_up(v7, d);             \
            if (lane >= rs + d) {                                           \
                v0 += u0; v1 += u1; v2 += u2; v3 += u3;                     \
                v4 += u4; v5 += u5; v6 += u6; v7 += u7;                     \
            }                                                               \
        }
        SCAN_STEP(1)
        SCAN_STEP(2)
        SCAN_STEP(4)
        SCAN_STEP(8)
        SCAN_STEP(16)
        SCAN_STEP(32)
#undef SCAN_STEP

        bool tail = (lane == 63) || ((hm >> (lane + 1)) & 1ull);
        if (tail) {
            float* p = ws + (long)bi * 8;
            atomicAdd(p + 0, v0);
            atomicAdd(p + 1, v1);
            atomicAdd(p + 2, v2);
            atomicAdd(p + 3, v3);
            atomicAdd(p + 4, v4);
            atomicAdd(p + 5, v5);
            atomicAdd(p + 6, v6);
            atomicAdd(p + 7, v7);
        }
    }
}

__global__ void finalize_kernel(const float* __restrict__ ws, float* __restrict__ out, int B) {
    int b = blockIdx.x * blockDim.x + threadIdx.x;
    if (b >= B) return;
    const float* p = ws + (long)b * 8;
    float s1x = p[0], s1y = p[1], s1z = p[2], s2 = p[3];
    float pxs = p[4], pys = p[5], pzs = p[6], m = p[7];
    float inv = (m > 0.0f) ? (1.0f / m) : 1.0f;
    float vx = s1x - s2 * (pxs * inv);
    float vy = s1y - s2 * (pys * inv);
    float vz = s1z - s2 * (pzs * inv);
    out[b] = sqrtf(vx * vx + vy * vy + vz * vz);
}

extern "C" void kernel_launch(void* const* d_in, const int* in_sizes, int n_in,
                              void* d_out, int out_size, void* d_ws, size_t ws_size,
                              hipStream_t stream) {
    const float* x     = (const float*)d_in[0];
    const float* pos   = (const float*)d_in[1];
    const float* W1    = (const float*)d_in[2];
    const float* b1    = (const float*)d_in[3];
    const float* W2    = (const float*)d_in[4];
    const float* b2    = (const float*)d_in[5];
    const float* am    = (const float*)d_in[6];
    const int*   z     = (const int*)d_in[7];
    const int*   batch = (const int*)d_in[8];

    const int N = in_sizes[7];
    const int B = out_size;
    float* ws    = (float*)d_ws;            // [B][8] accumulators (1 MB)
    float* xobuf = ws + (long)B * 8;        // [N] per-atom xo (4 MB); d_ws is ~2 GB
    float* out   = (float*)d_out;

    const int nChunks = (N + 63) / 64;

    int zn = B * 8;
    hipLaunchKernelGGL(zero_ws_kernel, dim3((zn + 255) / 256), dim3(256), 0, stream, ws, zn);

    int grid = nChunks < MAIN_GRID ? nChunks : MAIN_GRID;
    hipLaunchKernelGGL(mlp_kernel, dim3(grid), dim3(256), 0, stream,
                       x, W1, b1, W2, b2, xobuf, N, nChunks);

    hipLaunchKernelGGL(dipole_kernel, dim3(2048), dim3(256), 0, stream,
                       pos, am, z, batch, xobuf, ws, N, nChunks);

    hipLaunchKernelGGL(finalize_kernel, dim3((B + 255) / 256), dim3(256), 0, stream, ws, out, B);
}